// Round 10
// baseline (431.700 us; speedup 1.0000x reference)
//
#include <hip/hip_runtime.h>

#define DIN 128
#define BN_EPS 1e-5f

typedef __attribute__((ext_vector_type(8))) short bf16x8;
typedef __attribute__((ext_vector_type(4))) float f32x4;
typedef __attribute__((ext_vector_type(4))) unsigned u32x4;

__device__ __forceinline__ ushort f2bf(float f) {
    unsigned u = __float_as_uint(f);
    u += 0x7fffu + ((u >> 16) & 1u);
    return (ushort)(u >> 16);
}
__device__ __forceinline__ float bf2f(ushort h) {
    return __uint_as_float(((unsigned)h) << 16);
}

// ======== barrier-free streaming GEMM: C[M,N](bf16) = A[M,K] @ BT[N,K]^T ========
// B-fragments register-resident; A-strips (16 rows) streamed with one-strip
// prefetch double-buffer (loads for strip i+1 issued before MFMAs of strip i).
// CVT=0: A is bf16. CVT=1: A is fp32, converted in-register (round-half-up,
// high-half pack: ((a0+0x8000)>>16)|((a1+0x8000)&0xffff0000) ~ 2.5 ops/elem).
template<int KC, int STATS, int CVT>
__global__ __launch_bounds__(256) void gemm_wreg(
    const ushort* __restrict__ A, const float* __restrict__ A32,
    const ushort* __restrict__ BT,
    ushort* __restrict__ C, int mStrips, int N, int K, int logNG,
    float* __restrict__ gsums, float* __restrict__ gsqs)
{
    int tid = threadIdx.x;
    int lane = tid & 63;
    int gw = blockIdx.x * 4 + (tid >> 6);
    int wg = gw & ((1 << logNG) - 1);
    int set = gw >> logNG;
    int totalSets = (gridDim.x * 4) >> logNG;
    int cl = lane & 15, q = lane >> 4;
    int colBase = wg * 64;

    bf16x8 bf[4][KC];
    #pragma unroll
    for (int nt = 0; nt < 4; nt++) {
        const ushort* bp = BT + (long)(colBase + nt * 16 + cl) * K + q * 8;
        #pragma unroll
        for (int kc = 0; kc < KC; kc++)
            bf[nt][kc] = *(const bf16x8*)(bp + kc * 32);
    }

    float ssum[4] = {0.f, 0.f, 0.f, 0.f};
    float ssq[4]  = {0.f, 0.f, 0.f, 0.f};

    // raw staging: bf16 path uses bf16x8; fp32 path uses u32x4 pairs
    bf16x8 curH[KC], nxtH[KC];
    u32x4 curF[CVT ? 2 * KC : 1], nxtF[CVT ? 2 * KC : 1];

    int strip = set;
    if (strip < mStrips) {
        // load first strip
        if (CVT) {
            const unsigned* ap = (const unsigned*)(A32 + (long)(strip * 16 + cl) * K + q * 8);
            #pragma unroll
            for (int kc = 0; kc < KC; kc++) {
                curF[2 * kc + 0] = *(const u32x4*)(ap + kc * 32);
                curF[2 * kc + 1] = *(const u32x4*)(ap + kc * 32 + 4);
            }
        } else {
            const ushort* ap = A + (long)(strip * 16 + cl) * K + q * 8;
            #pragma unroll
            for (int kc = 0; kc < KC; kc++)
                curH[kc] = *(const bf16x8*)(ap + kc * 32);
        }

        for (;;) {
            int next = strip + totalSets;
            bool has = next < mStrips;
            if (has) {
                if (CVT) {
                    const unsigned* ap = (const unsigned*)(A32 + (long)(next * 16 + cl) * K + q * 8);
                    #pragma unroll
                    for (int kc = 0; kc < KC; kc++) {
                        nxtF[2 * kc + 0] = *(const u32x4*)(ap + kc * 32);
                        nxtF[2 * kc + 1] = *(const u32x4*)(ap + kc * 32 + 4);
                    }
                } else {
                    const ushort* ap = A + (long)(next * 16 + cl) * K + q * 8;
                    #pragma unroll
                    for (int kc = 0; kc < KC; kc++)
                        nxtH[kc] = *(const bf16x8*)(ap + kc * 32);
                }
            }

            // build A fragments for current strip
            bf16x8 af[KC];
            if (CVT) {
                #pragma unroll
                for (int kc = 0; kc < KC; kc++) {
                    unsigned* o = (unsigned*)&af[kc];
                    #pragma unroll
                    for (int p = 0; p < 2; p++) {
                        u32x4 r = curF[2 * kc + p];
                        unsigned a0 = r[0] + 0x8000u, a1 = r[1] + 0x8000u;
                        unsigned a2 = r[2] + 0x8000u, a3 = r[3] + 0x8000u;
                        o[2 * p + 0] = (a0 >> 16) | (a1 & 0xffff0000u);
                        o[2 * p + 1] = (a2 >> 16) | (a3 & 0xffff0000u);
                    }
                }
            } else {
                #pragma unroll
                for (int kc = 0; kc < KC; kc++) af[kc] = curH[kc];
            }

            f32x4 acc[4] = {};
            #pragma unroll
            for (int kc = 0; kc < KC; kc++)
                #pragma unroll
                for (int nt = 0; nt < 4; nt++)
                    acc[nt] = __builtin_amdgcn_mfma_f32_16x16x32_bf16(af[kc], bf[nt][kc], acc[nt], 0, 0, 0);

            int rowBase = strip * 16;
            #pragma unroll
            for (int nt = 0; nt < 4; nt++) {
                #pragma unroll
                for (int r = 0; r < 4; r++) {
                    float v = acc[nt][r];
                    long row = rowBase + q * 4 + r;
                    C[row * N + colBase + nt * 16 + cl] = f2bf(v);
                    if (STATS) { ssum[nt] += v; ssq[nt] += v * v; }
                }
            }

            if (!has) break;
            if (CVT) {
                #pragma unroll
                for (int i = 0; i < 2 * KC; i++) curF[i] = nxtF[i];
            } else {
                #pragma unroll
                for (int kc = 0; kc < KC; kc++) curH[kc] = nxtH[kc];
            }
            strip = next;
        }
    }

    if (STATS) {
        #pragma unroll
        for (int nt = 0; nt < 4; nt++) {
            ssum[nt] += __shfl_xor(ssum[nt], 16, 64);
            ssum[nt] += __shfl_xor(ssum[nt], 32, 64);
            ssq[nt]  += __shfl_xor(ssq[nt], 16, 64);
            ssq[nt]  += __shfl_xor(ssq[nt], 32, 64);
        }
        if (q == 0) {
            #pragma unroll
            for (int nt = 0; nt < 4; nt++) {
                atomicAdd(&gsums[colBase + nt * 16 + cl], ssum[nt]);
                atomicAdd(&gsqs[colBase + nt * 16 + cl], ssq[nt]);
            }
        }
    }
}

// ======== BN params ========
__global__ void bnparam_kernel(const float* __restrict__ sums, const float* __restrict__ sqs,
                               const float* __restrict__ gamma, const float* __restrict__ beta,
                               float* __restrict__ scale, float* __restrict__ shift,
                               int N, float invM)
{
    int c = blockIdx.x * blockDim.x + threadIdx.x;
    if (c < N) {
        float mean = sums[c] * invM;
        float var = sqs[c] * invM - mean * mean;
        float sc = gamma[c] * rsqrtf(var + BN_EPS);
        scale[c] = sc;
        shift[c] = beta[c] - mean * sc;
    }
}

// ======== BN + act, bf16 -> bf16 (x4 vector), input contiguous, output strided ========
__global__ __launch_bounds__(256) void bnact_bf16(
    const ushort* __restrict__ X, const float* __restrict__ scale, const float* __restrict__ shift,
    ushort* __restrict__ O, int total4, int logN, int outStride, float negSlope)
{
    int stride = gridDim.x * blockDim.x;
    int Nm1 = (1 << logN) - 1;
    for (int t = blockIdx.x * blockDim.x + threadIdx.x; t < total4; t += stride) {
        int idx = t * 4;
        int row = idx >> logN;
        int c = idx & Nm1;
        ushort4 v4 = *(const ushort4*)&X[idx];
        float4 sc = *(const float4*)&scale[c];
        float4 sh = *(const float4*)&shift[c];
        float a = bf2f(v4.x) * sc.x + sh.x; a = (a > 0.f) ? a : a * negSlope;
        float b = bf2f(v4.y) * sc.y + sh.y; b = (b > 0.f) ? b : b * negSlope;
        float d = bf2f(v4.z) * sc.z + sh.z; d = (d > 0.f) ? d : d * negSlope;
        float e = bf2f(v4.w) * sc.w + sh.w; e = (e > 0.f) ? e : e * negSlope;
        ushort4 o; o.x = f2bf(a); o.y = f2bf(b); o.z = f2bf(d); o.w = f2bf(e);
        *(ushort4*)&O[(long)row * outStride + c] = o;
    }
}

// ======== BN + act, fp32 in-place (final output) ========
__global__ __launch_bounds__(256) void bnact_f32(
    float* __restrict__ X, const float* __restrict__ scale, const float* __restrict__ shift,
    int total4, int logN, float negSlope)
{
    int stride = gridDim.x * blockDim.x;
    int Nm1 = (1 << logN) - 1;
    for (int t = blockIdx.x * blockDim.x + threadIdx.x; t < total4; t += stride) {
        int idx = t * 4;
        int c = idx & Nm1;
        float4 v = *(const float4*)&X[idx];
        float4 sc = *(const float4*)&scale[c];
        float4 sh = *(const float4*)&shift[c];
        float a = v.x * sc.x + sh.x; a = (a > 0.f) ? a : a * negSlope;
        float b = v.y * sc.y + sh.y; b = (b > 0.f) ? b : b * negSlope;
        float d = v.z * sc.z + sh.z; d = (d > 0.f) ? d : d * negSlope;
        float e = v.w * sc.w + sh.w; e = (e > 0.f) ? e : e * negSlope;
        *(float4*)&X[idx] = make_float4(a, b, d, e);
    }
}

// ======== column stats for final output (128 cols, register accum) ========
__global__ __launch_bounds__(256) void colstats128(
    const float* __restrict__ X, float* __restrict__ sums, float* __restrict__ sqs, int M)
{
    __shared__ float ss[128], sq[128];
    int tid = threadIdx.x;
    if (tid < 128) { ss[tid] = 0.f; sq[tid] = 0.f; }
    __syncthreads();
    int cg = tid & 31;
    int worker = (blockIdx.x << 3) | (tid >> 5);
    int totalW = gridDim.x << 3;
    float4 s4 = make_float4(0, 0, 0, 0), q4 = make_float4(0, 0, 0, 0);
    for (int r = worker; r < M; r += totalW) {
        float4 v = *(const float4*)&X[(long)r * 128 + cg * 4];
        s4.x += v.x; s4.y += v.y; s4.z += v.z; s4.w += v.w;
        q4.x += v.x * v.x; q4.y += v.y * v.y; q4.z += v.z * v.z; q4.w += v.w * v.w;
    }
    atomicAdd(&ss[cg * 4 + 0], s4.x); atomicAdd(&sq[cg * 4 + 0], q4.x);
    atomicAdd(&ss[cg * 4 + 1], s4.y); atomicAdd(&sq[cg * 4 + 1], q4.y);
    atomicAdd(&ss[cg * 4 + 2], s4.z); atomicAdd(&sq[cg * 4 + 2], q4.z);
    atomicAdd(&ss[cg * 4 + 3], s4.w); atomicAdd(&sq[cg * 4 + 3], q4.w);
    __syncthreads();
    if (tid < 128) { atomicAdd(&sums[tid], ss[tid]); atomicAdd(&sqs[tid], sq[tid]); }
}

__global__ void wt_all(const float* __restrict__ W0, const float* __restrict__ W1,
                       const float* __restrict__ W2, const float* __restrict__ W3,
                       const float* __restrict__ W4, const float* __restrict__ W5,
                       ushort* __restrict__ WT)
{
    int seg = blockIdx.y;
    const float* W; int logK, dstBase, stride, kOff;
    switch (seg) {
        case 0: W = W0; logK = 7; dstBase = 0;      stride = 128; kOff = 0;   break;
        case 1: W = W1; logK = 8; dstBase = 32768;  stride = 256; kOff = 0;   break;
        case 2: W = W2; logK = 7; dstBase = 65536;  stride = 256; kOff = 0;   break;
        case 3: W = W3; logK = 7; dstBase = 65536;  stride = 256; kOff = 128; break;
        case 4: W = W4; logK = 8; dstBase = 131072; stride = 256; kOff = 0;   break;
        default:W = W5; logK = 8; dstBase = 163840; stride = 256; kOff = 0;   break;
    }
    int t = blockIdx.x * blockDim.x + threadIdx.x;
    int N = 32768 >> logK;
    int k = t & ((1 << logK) - 1);
    int n = t >> logK;
    WT[(long)dstBase + (long)n * stride + kOff + k] = f2bf(W[(long)k * N + n]);
}

// ======== CSR build ========
__global__ void degcount_kernel(const int* __restrict__ dst, int* __restrict__ degi, int E)
{
    int i = blockIdx.x * blockDim.x + threadIdx.x;
    if (i < E) atomicAdd(&degi[dst[i]], 1);
}

__global__ __launch_bounds__(256) void scan_block_sums(const int* __restrict__ degi,
                                                       int* __restrict__ partial, int n)
{
    __shared__ int s[256];
    int i = blockIdx.x * 256 + threadIdx.x;
    s[threadIdx.x] = (i < n) ? degi[i] : 0;
    __syncthreads();
    for (int off = 128; off > 0; off >>= 1) {
        if (threadIdx.x < off) s[threadIdx.x] += s[threadIdx.x + off];
        __syncthreads();
    }
    if (threadIdx.x == 0) partial[blockIdx.x] = s[0];
}

__global__ __launch_bounds__(256) void scan_partials(int* __restrict__ partial, int nb)
{
    __shared__ int s[256];
    int v = (threadIdx.x < nb) ? partial[threadIdx.x] : 0;
    s[threadIdx.x] = v;
    __syncthreads();
    for (int off = 1; off < 256; off <<= 1) {
        int t = (threadIdx.x >= off) ? s[threadIdx.x - off] : 0;
        __syncthreads();
        s[threadIdx.x] += t;
        __syncthreads();
    }
    if (threadIdx.x < nb) partial[threadIdx.x] = s[threadIdx.x] - v;
}

__global__ __launch_bounds__(256) void scan_final(const int* __restrict__ degi,
                                                  const int* __restrict__ partial,
                                                  int* __restrict__ rowstart, int n)
{
    __shared__ int s[256];
    int i = blockIdx.x * 256 + threadIdx.x;
    int v = (i < n) ? degi[i] : 0;
    s[threadIdx.x] = v;
    __syncthreads();
    for (int off = 1; off < 256; off <<= 1) {
        int t = (threadIdx.x >= off) ? s[threadIdx.x - off] : 0;
        __syncthreads();
        s[threadIdx.x] += t;
        __syncthreads();
    }
    if (i < n) rowstart[i] = partial[blockIdx.x] + s[threadIdx.x] - v;
}

__global__ void fillcsr_kernel(const int* __restrict__ src, const int* __restrict__ dst,
                               const int* __restrict__ rowstart, int* __restrict__ cursor,
                               int* __restrict__ csr, int E)
{
    int i = blockIdx.x * blockDim.x + threadIdx.x;
    if (i < E) {
        int d = dst[i];
        int p = atomicAdd(&cursor[d], 1);
        csr[rowstart[d] + p] = src[i];
    }
}

// ======== gather mean (bf16 in/out), one wave per node, 128 cols, unroll-4 MLP ========
__global__ __launch_bounds__(256) void gather_bf(
    const ushort* __restrict__ X, const int* __restrict__ rowstart,
    const int* __restrict__ degi, const int* __restrict__ csr,
    ushort* __restrict__ O, int nN)
{
    int wv = (blockIdx.x * blockDim.x + threadIdx.x) >> 6;
    int lane = threadIdx.x & 63;
    if (wv >= nN) return;
    int start = rowstart[wv], d = degi[wv];
    float a0 = 0.f, a1 = 0.f;
    int col = lane * 2;
    int j = 0;
    for (; j + 4 <= d; j += 4) {
        int s0 = csr[start + j + 0];
        int s1 = csr[start + j + 1];
        int s2 = csr[start + j + 2];
        int s3 = csr[start + j + 3];
        unsigned p0 = *(const unsigned*)(X + (long)s0 * 256 + col);
        unsigned p1 = *(const unsigned*)(X + (long)s1 * 256 + col);
        unsigned p2 = *(const unsigned*)(X + (long)s2 * 256 + col);
        unsigned p3 = *(const unsigned*)(X + (long)s3 * 256 + col);
        a0 += bf2f((ushort)(p0 & 0xffff)) + bf2f((ushort)(p1 & 0xffff))
            + bf2f((ushort)(p2 & 0xffff)) + bf2f((ushort)(p3 & 0xffff));
        a1 += bf2f((ushort)(p0 >> 16)) + bf2f((ushort)(p1 >> 16))
            + bf2f((ushort)(p2 >> 16)) + bf2f((ushort)(p3 >> 16));
    }
    for (; j < d; j++) {
        int s0 = csr[start + j];
        unsigned p0 = *(const unsigned*)(X + (long)s0 * 256 + col);
        a0 += bf2f((ushort)(p0 & 0xffff));
        a1 += bf2f((ushort)(p0 >> 16));
    }
    float inv = 1.f / fmaxf((float)d, 1.f);
    unsigned o = (unsigned)f2bf(a0 * inv) | ((unsigned)f2bf(a1 * inv) << 16);
    *(unsigned*)(O + (long)wv * 256 + col) = o;
}

// ======== fused gather2: out = mean(Z[src, 0:128]) + Z[dst, 128:256], unroll-4 ========
__global__ __launch_bounds__(256) void gather_fuse(
    const ushort* __restrict__ Z, const int* __restrict__ rowstart,
    const int* __restrict__ degi, const int* __restrict__ csr,
    float* __restrict__ O, int nN)
{
    int wv = (blockIdx.x * blockDim.x + threadIdx.x) >> 6;
    int lane = threadIdx.x & 63;
    if (wv >= nN) return;
    int start = rowstart[wv], d = degi[wv];
    float a0 = 0.f, a1 = 0.f;
    int col = lane * 2;
    int j = 0;
    for (; j + 4 <= d; j += 4) {
        int s0 = csr[start + j + 0];
        int s1 = csr[start + j + 1];
        int s2 = csr[start + j + 2];
        int s3 = csr[start + j + 3];
        unsigned p0 = *(const unsigned*)(Z + (long)s0 * 256 + col);
        unsigned p1 = *(const unsigned*)(Z + (long)s1 * 256 + col);
        unsigned p2 = *(const unsigned*)(Z + (long)s2 * 256 + col);
        unsigned p3 = *(const unsigned*)(Z + (long)s3 * 256 + col);
        a0 += bf2f((ushort)(p0 & 0xffff)) + bf2f((ushort)(p1 & 0xffff))
            + bf2f((ushort)(p2 & 0xffff)) + bf2f((ushort)(p3 & 0xffff));
        a1 += bf2f((ushort)(p0 >> 16)) + bf2f((ushort)(p1 >> 16))
            + bf2f((ushort)(p2 >> 16)) + bf2f((ushort)(p3 >> 16));
    }
    for (; j < d; j++) {
        int s0 = csr[start + j];
        unsigned p0 = *(const unsigned*)(Z + (long)s0 * 256 + col);
        a0 += bf2f((ushort)(p0 & 0xffff));
        a1 += bf2f((ushort)(p0 >> 16));
    }
    float inv = 1.f / fmaxf((float)d, 1.f);
    unsigned sv = *(const unsigned*)(Z + (long)wv * 256 + 128 + col);
    float s0 = bf2f((ushort)(sv & 0xffff));
    float s1 = bf2f((ushort)(sv >> 16));
    *(float2*)(O + (long)wv * 128 + col) = make_float2(a0 * inv + s0, a1 * inv + s1);
}

extern "C" void kernel_launch(void* const* d_in, const int* in_sizes, int n_in,
                              void* d_out, int out_size, void* d_ws, size_t ws_size,
                              hipStream_t stream)
{
    const float* nodes = (const float*)d_in[0];
    const int*   src   = (const int*)d_in[1];
    const int*   dst   = (const int*)d_in[2];
    const float* Wf1   = (const float*)d_in[3];
    const float* gf1   = (const float*)d_in[5];
    const float* bef1  = (const float*)d_in[6];
    const float* Wf2   = (const float*)d_in[7];
    const float* gf2   = (const float*)d_in[9];
    const float* bef2  = (const float*)d_in[10];
    const float* Ws1   = (const float*)d_in[11];
    const float* Wn1   = (const float*)d_in[12];
    const float* gs1   = (const float*)d_in[14];
    const float* bs1   = (const float*)d_in[15];
    const float* Ws2   = (const float*)d_in[16];
    const float* Wn2   = (const float*)d_in[17];
    const float* gs2   = (const float*)d_in[19];
    const float* bs2   = (const float*)d_in[20];
    // pre-BN biases (bf1,bf2,b1,b2) cancel under BatchNorm -> skipped

    int nN = in_sizes[0] / DIN;   // 50000
    int nE = in_sizes[1];         // 600000
    float* out = (float*)d_out;
    int mStrips = nN / 16;        // 3125 (exact)

    // ---- workspace (round-8 layout) ----
    ushort* PRE = (ushort*)d_ws;                      // nN*256 bf16 pre-BN GEMM out
    ushort* BF1 = PRE + (size_t)nN * 256;             // nN*256 bf16 (X1 / h1)
    ushort* BF2 = BF1 + (size_t)nN * 256;             // nN*256 bf16 ([h|agg] / Z)
    float* stats = (float*)(BF2 + (size_t)nN * 256);  // 2048 floats, 4 layer-regions
    float* scale = stats + 2048;                      // 256
    float* shift = scale + 256;                       // 256
    ushort* WT   = (ushort*)(shift + 256);            // 196608 shorts
    int* degi     = (int*)(WT + 196608);              // nN
    int* cursor   = degi + nN;                        // nN (adjacent: one memset)
    int* rowstart = cursor + nN;                      // nN
    int* partial  = rowstart + nN;                    // 256
    int* csr      = partial + 256;                    // nE

    ushort* Wf1T = WT;
    ushort* Wf2T = WT + 32768;
    ushort* Wc1T = WT + 65536;
    ushort* Wc2T = WT + 131072;

    dim3 blk(256);
    auto cdiv = [](int a, int b) { return (a + b - 1) / b; };
    int nScanBlocks = cdiv(nN, 256);

    // ---- weight transpose + zero-init ----
    wt_all<<<dim3(128, 6), blk, 0, stream>>>(Wf1, Wf2, Ws1, Wn1, Wn2, Ws2, WT);
    hipMemsetAsync(stats, 0, 2048 * sizeof(float), stream);
    hipMemsetAsync(degi, 0, 2 * (size_t)nN * sizeof(int), stream);

    // ---- CSR build ----
    degcount_kernel<<<dim3(cdiv(nE, 256)), blk, 0, stream>>>(dst, degi, nE);
    scan_block_sums<<<dim3(nScanBlocks), blk, 0, stream>>>(degi, partial, nN);
    scan_partials<<<dim3(1), blk, 0, stream>>>(partial, nScanBlocks);
    scan_final<<<dim3(nScanBlocks), blk, 0, stream>>>(degi, partial, rowstart, nN);
    fillcsr_kernel<<<dim3(cdiv(nE, 256)), blk, 0, stream>>>(src, dst, rowstart, cursor, csr, nE);

    // ---- FF1: PRE = cvt(nodes) @ Wf1T (fp32 A inline-converted; K=128, N=256, stats->L0) ----
    gemm_wreg<4, 1, 1><<<dim3(512), blk, 0, stream>>>(
        nullptr, nodes, Wf1T, PRE, mStrips, 256, 128, 2, stats, stats + 256);
    bnparam_kernel<<<dim3(1), blk, 0, stream>>>(stats, stats + 256, gf1, bef1, scale, shift, 256, 1.0f / nN);
    bnact_bf16<<<dim3(2048), blk, 0, stream>>>(PRE, scale, shift, BF1, nN * 256 / 4, 8, 256, 0.0f);

    // ---- FF2: PRE = BF1 @ Wf2T (K=256, N=128, stats->L1) ; BN+ReLU -> BF2[:,0:128] ----
    gemm_wreg<8, 1, 0><<<dim3(512), blk, 0, stream>>>(
        BF1, nullptr, Wf2T, PRE, mStrips, 128, 256, 1, stats + 512, stats + 768);
    bnparam_kernel<<<dim3(1), blk, 0, stream>>>(stats + 512, stats + 768, gf2, bef2, scale, shift, 128, 1.0f / nN);
    bnact_bf16<<<dim3(2048), blk, 0, stream>>>(PRE, scale, shift, BF2, nN * 128 / 4, 7, 256, 0.0f);

    // ---- gather1: BF2[:,128:256] = mean-gather(BF2[:,0:128]) ----
    gather_bf<<<dim3(cdiv(nN * 64, 256)), blk, 0, stream>>>(BF2, rowstart, degi, csr, BF2 + 128, nN);

    // ---- SAGE1: PRE = [h|agg] @ [Ws1;Wn1] (K=256, N=256, stats->L2) ; BN+LReLU -> BF1 (h1) ----
    gemm_wreg<8, 1, 0><<<dim3(512), blk, 0, stream>>>(
        BF2, nullptr, Wc1T, PRE, mStrips, 256, 256, 2, stats + 1024, stats + 1280);
    bnparam_kernel<<<dim3(1), blk, 0, stream>>>(stats + 1024, stats + 1280, gs1, bs1, scale, shift, 256, 1.0f / nN);
    bnact_bf16<<<dim3(2048), blk, 0, stream>>>(PRE, scale, shift, BF1, nN * 256 / 4, 8, 256, 0.01f);

    // ---- SAGE2: BF2 = h1 @ [Wn2|Ws2] (K=256, N=256, no stats) ; gather_fuse -> out(fp32) ----
    gemm_wreg<8, 0, 0><<<dim3(512), blk, 0, stream>>>(
        BF1, nullptr, Wc2T, BF2, mStrips, 256, 256, 2, nullptr, nullptr);
    gather_fuse<<<dim3(cdiv(nN * 64, 256)), blk, 0, stream>>>(BF2, rowstart, degi, csr, out, nN);

    // ---- final: colstats -> BN params -> BN+LReLU on out ----
    colstats128<<<dim3(120), blk, 0, stream>>>(out, stats + 1536, stats + 1792, nN);
    bnparam_kernel<<<dim3(1), blk, 0, stream>>>(stats + 1536, stats + 1792, gs2, bs2, scale, shift, 128, 1.0f / nN);
    bnact_f32<<<dim3(2048), blk, 0, stream>>>(out, scale, shift, nN * 128 / 4, 7, 0.01f);
}